// Round 1
// baseline (672.289 us; speedup 1.0000x reference)
//
#include <hip/hip_runtime.h>
#include <hip/hip_bf16.h>

// Problem: MultiAttnMatch — cross attention
// B=16, L1=1024, L2=1024, DIN=1024, H=16, DK=DV=64
#define BATCH 16
#define L1D 1024
#define L2D 1024
#define DIN 1024
#define NH 16
#define DKD 64
#define HD 1024  // NH*DK = NH*DV

typedef __attribute__((ext_vector_type(4))) float floatx4;
typedef __attribute__((ext_vector_type(8))) short shortx8;
typedef __attribute__((ext_vector_type(8))) unsigned short ushortx8;
typedef __attribute__((ext_vector_type(4))) unsigned short ushortx4;

static __device__ __forceinline__ unsigned short f2bf(float f) {
    union { float f; unsigned u; } v; v.f = f;
    unsigned r = v.u + 0x7fff + ((v.u >> 16) & 1);   // RNE
    return (unsigned short)(r >> 16);
}

// ---------------------------------------------------------------------------
// Kernel 1: W [DIN][HD] fp32  ->  Wt [HD][DIN] bf16 (transpose + convert)
// ---------------------------------------------------------------------------
__global__ void wt_kernel(const float* __restrict__ W, unsigned short* __restrict__ Wt) {
    __shared__ float tile[32][33];
    int bx = blockIdx.x;          // n tile
    int by = blockIdx.y;          // k tile
    int tx = threadIdx.x;         // 0..31
    int ty = threadIdx.y;         // 0..7
    for (int i = 0; i < 4; i++) {
        int k = by * 32 + ty + i * 8;
        tile[ty + i * 8][tx] = W[(size_t)k * HD + bx * 32 + tx];
    }
    __syncthreads();
    for (int i = 0; i < 4; i++) {
        int n = bx * 32 + ty + i * 8;
        Wt[(size_t)n * DIN + by * 32 + tx] = f2bf(tile[tx][ty + i * 8]);
    }
}

// ---------------------------------------------------------------------------
// Kernel 2: GEMM  Out[m][n] = bf16( X[m][:] @ W[:][n] + bias[n] )
//   X:  [M][DIN] fp32 (M = 16384)
//   Wt: [HD][DIN] bf16  (pre-transposed: n-major, k-contiguous)
//   Out:[M][HD] bf16
// Tile 128x128, BK=32, 4 waves (2x2 of 64x64), 16x16x32 bf16 MFMA.
// ---------------------------------------------------------------------------
#define BM 128
#define BN 128
#define BK 32
#define ASTR 40   // bf16 elems; 80 B row stride: 16B aligned, 2-way banks (free)

__global__ __launch_bounds__(256, 2) void gemm_kernel(
    const float* __restrict__ Xp, const unsigned short* __restrict__ Wt,
    const float* __restrict__ bias, unsigned short* __restrict__ Out)
{
    __shared__ unsigned short As[BM * ASTR];
    __shared__ unsigned short Bs[BN * ASTR];
    const int m0 = blockIdx.y * BM;
    const int n0 = blockIdx.x * BN;
    const int tid = threadIdx.x;
    const int wid = tid >> 6;
    const int lane = tid & 63;
    const int c = lane & 15;       // col-in-subtile / m-row for A frag
    const int qd = lane >> 4;      // quad
    const int wm = (wid >> 1) * 64;
    const int wn = (wid & 1) * 64;

    floatx4 acc[4][4] = {};

    for (int k0 = 0; k0 < DIN; k0 += BK) {
        // stage A: 128 rows x 32 cols, fp32 -> bf16
        for (int i = 0; i < 4; i++) {
            int idx = i * 256 + tid;
            int row = idx >> 3;
            int col = (idx & 7) * 4;
            const float4 v = *(const float4*)(Xp + (size_t)(m0 + row) * DIN + k0 + col);
            ushortx4 s4;
            s4[0] = f2bf(v.x); s4[1] = f2bf(v.y); s4[2] = f2bf(v.z); s4[3] = f2bf(v.w);
            *(ushortx4*)(&As[row * ASTR + col]) = s4;
        }
        // stage B (Wt rows n0..n0+127, cols k0..k0+31), bf16 16B loads
        for (int i = 0; i < 2; i++) {
            int idx = i * 256 + tid;
            int row = idx >> 2;
            int col = (idx & 3) * 8;
            *(ushortx8*)(&Bs[row * ASTR + col]) =
                *(const ushortx8*)(Wt + (size_t)(n0 + row) * DIN + k0 + col);
        }
        __syncthreads();

        shortx8 a[4], b[4];
        for (int mt = 0; mt < 4; mt++)
            a[mt] = *(shortx8*)(&As[(wm + mt * 16 + c) * ASTR + qd * 8]);
        for (int nt = 0; nt < 4; nt++)
            b[nt] = *(shortx8*)(&Bs[(wn + nt * 16 + c) * ASTR + qd * 8]);
        for (int mt = 0; mt < 4; mt++)
            for (int nt = 0; nt < 4; nt++)
                acc[mt][nt] = __builtin_amdgcn_mfma_f32_16x16x32_bf16(
                    a[mt], b[nt], acc[mt][nt], 0, 0, 0);
        __syncthreads();
    }

    // epilogue: C/D layout col=lane&15, row=quad*4+r
    for (int nt = 0; nt < 4; nt++) {
        int gn = n0 + wn + nt * 16 + c;
        float bv = bias[gn];
        for (int mt = 0; mt < 4; mt++) {
            for (int r = 0; r < 4; r++) {
                int gm = m0 + wm + mt * 16 + qd * 4 + r;
                Out[(size_t)gm * HD + gn] = f2bf(acc[mt][nt][r] + bv);
            }
        }
    }
}

// ---------------------------------------------------------------------------
// Kernel 3: V [b*L2+l2][h*64+dv] bf16 -> Vt [(b*16+h)*64+dv][l2] bf16
// ---------------------------------------------------------------------------
__global__ void vt_kernel(const unsigned short* __restrict__ V,
                          unsigned short* __restrict__ Vt) {
    __shared__ unsigned short t[64][72];
    const int l20 = blockIdx.x * 64;
    const int bh  = blockIdx.y;
    const int b   = bh >> 4, h = bh & 15;
    const int tid = threadIdx.x;
    for (int i = 0; i < 2; i++) {
        int idx = i * 256 + tid;
        int row = idx >> 3, col = (idx & 7) * 8;
        *(ushortx8*)(&t[row][col]) =
            *(const ushortx8*)(V + (size_t)(b * L2D + l20 + row) * HD + h * 64 + col);
    }
    __syncthreads();
    for (int i = 0; i < 2; i++) {
        int idx = i * 256 + tid;
        int dv = idx >> 3, col = (idx & 7) * 8;
        ushortx8 v;
        for (int j = 0; j < 8; j++) v[j] = t[col + j][dv];
        *(ushortx8*)(Vt + (size_t)(bh * 64 + dv) * L2D + l20 + col) = v;
    }
}

// ---------------------------------------------------------------------------
// Kernel 4: flash attention per (b,h), 64 Q-rows per block, KV tiles of 64.
//   Q,K: [b*len+l][h*64+d] bf16 ; Vt: [(b*16+h)*64+dv][l2] bf16
//   mask: [b][l2] int32 (nonzero => -inf)
//   out: [b][l1][h*64+dv] fp32
// ---------------------------------------------------------------------------
__global__ __launch_bounds__(256, 2) void attn_kernel(
    const unsigned short* __restrict__ Q, const unsigned short* __restrict__ K,
    const unsigned short* __restrict__ Vt, const int* __restrict__ mask,
    float* __restrict__ out)
{
    __shared__ unsigned short Ks[64 * 72];
    __shared__ unsigned short Vs[64 * 72];
    __shared__ unsigned short Ps[4][16 * 72];

    const int q0  = blockIdx.x * 64;
    const int bh  = blockIdx.y;
    const int b   = bh >> 4, h = bh & 15;
    const int tid = threadIdx.x, wid = tid >> 6, lane = tid & 63;
    const int c = lane & 15, qd = lane >> 4;

    // Q A-fragments for this wave's 16 rows (k-contiguous in global: direct load)
    const int qrow = q0 + wid * 16 + c;
    shortx8 qf[2];
    for (int kt = 0; kt < 2; kt++)
        qf[kt] = *(const shortx8*)(Q + (size_t)(b * L1D + qrow) * HD + h * 64 + kt * 32 + qd * 8);

    floatx4 o[4] = {};
    float mrow[4], lrow[4];
    for (int r = 0; r < 4; r++) { mrow[r] = -INFINITY; lrow[r] = 0.f; }

    const unsigned short* Kbase = K + (size_t)b * L2D * HD + h * 64;
    const unsigned short* Vbase = Vt + (size_t)bh * 64 * L2D;
    const int* mb = mask + b * L2D;

    for (int kv0 = 0; kv0 < L2D; kv0 += 64) {
        // stage K tile [l2][dk] and Vt tile [dv][l2]
        for (int i = 0; i < 2; i++) {
            int idx = i * 256 + tid;
            int row = idx >> 3, col = (idx & 7) * 8;
            *(ushortx8*)(&Ks[row * 72 + col]) =
                *(const ushortx8*)(Kbase + (size_t)(kv0 + row) * HD + col);
            *(ushortx8*)(&Vs[row * 72 + col]) =
                *(const ushortx8*)(Vbase + (size_t)row * L2D + kv0 + col);
        }
        __syncthreads();

        // S = Q K^T (per wave: 16 x 64), C-layout
        floatx4 s[4];
        for (int nt = 0; nt < 4; nt++) {
            floatx4 z = {};
            for (int kt = 0; kt < 2; kt++) {
                shortx8 bf = *(shortx8*)(&Ks[(nt * 16 + c) * 72 + kt * 32 + qd * 8]);
                z = __builtin_amdgcn_mfma_f32_16x16x32_bf16(qf[kt], bf, z, 0, 0, 0);
            }
            s[nt] = z;
        }
        // scale + mask
        for (int nt = 0; nt < 4; nt++) {
            bool msk = (mb[kv0 + nt * 16 + c] != 0);
            for (int r = 0; r < 4; r++)
                s[nt][r] = msk ? -INFINITY : s[nt][r] * 0.125f;
        }
        // per-row tile max (reduce over nt, then 16 lanes within quad group)
        float alpha[4], msafe[4];
        for (int r = 0; r < 4; r++) {
            float v = fmaxf(fmaxf(s[0][r], s[1][r]), fmaxf(s[2][r], s[3][r]));
            for (int off = 1; off < 16; off <<= 1)
                v = fmaxf(v, __shfl_xor(v, off, 64));
            float mnew = fmaxf(mrow[r], v);
            msafe[r] = (mnew == -INFINITY) ? 0.f : mnew;
            alpha[r] = __expf(mrow[r] - msafe[r]);   // mrow=-inf -> 0
            mrow[r] = mnew;
        }
        // P = exp(S - m), partial row sums
        float psum[4] = {0.f, 0.f, 0.f, 0.f};
        for (int nt = 0; nt < 4; nt++)
            for (int r = 0; r < 4; r++) {
                float p = __expf(s[nt][r] - msafe[r]);
                psum[r] += p;
                s[nt][r] = p;
            }
        // write P (C-layout) to LDS as bf16 for A-layout re-read
        for (int nt = 0; nt < 4; nt++)
            for (int r = 0; r < 4; r++)
                Ps[wid][(qd * 4 + r) * 72 + nt * 16 + c] = f2bf(s[nt][r]);
        // l update
        for (int r = 0; r < 4; r++) {
            float v = psum[r];
            for (int off = 1; off < 16; off <<= 1)
                v += __shfl_xor(v, off, 64);
            lrow[r] = lrow[r] * alpha[r] + v;
        }
        // rescale O
        for (int nt = 0; nt < 4; nt++)
            for (int r = 0; r < 4; r++)
                o[nt][r] *= alpha[r];
        // O += P @ V  (P A-frags from this wave's private LDS region)
        shortx8 pf[2];
        for (int kt = 0; kt < 2; kt++)
            pf[kt] = *(shortx8*)(&Ps[wid][c * 72 + kt * 32 + qd * 8]);
        for (int nt = 0; nt < 4; nt++)
            for (int kt = 0; kt < 2; kt++) {
                shortx8 vf = *(shortx8*)(&Vs[(nt * 16 + c) * 72 + kt * 32 + qd * 8]);
                o[nt] = __builtin_amdgcn_mfma_f32_16x16x32_bf16(pf[kt], vf, o[nt], 0, 0, 0);
            }
        __syncthreads();
    }

    // epilogue: out rows q0+wid*16+qd*4+r, cols h*64 + nt*16 + c, fp32
    for (int r = 0; r < 4; r++) {
        float inv = 1.f / lrow[r];
        size_t rowbase = ((size_t)b * L1D + q0 + wid * 16 + qd * 4 + r) * HD + h * 64;
        for (int nt = 0; nt < 4; nt++)
            out[rowbase + nt * 16 + c] = o[nt][r] * inv;
    }
}

// ---------------------------------------------------------------------------
extern "C" void kernel_launch(void* const* d_in, const int* in_sizes, int n_in,
                              void* d_out, int out_size, void* d_ws, size_t ws_size,
                              hipStream_t stream) {
    const float* x  = (const float*)d_in[0];
    const float* y  = (const float*)d_in[1];
    const int*  ym  = (const int*)d_in[2];
    const float* Wq = (const float*)d_in[3];
    const float* bq = (const float*)d_in[4];
    const float* Wk = (const float*)d_in[5];
    const float* bk = (const float*)d_in[6];
    const float* Wv = (const float*)d_in[7];
    const float* bv = (const float*)d_in[8];
    float* outp = (float*)d_out;

    const size_t M = (size_t)BATCH * L1D;   // 16384
    unsigned short* Qb  = (unsigned short*)d_ws;
    unsigned short* Kb  = Qb  + M * HD;
    unsigned short* Vb  = Kb  + M * HD;
    unsigned short* Vtb = Vb  + M * HD;
    unsigned short* Wtq = Vtb + M * HD;
    unsigned short* Wtk = Wtq + (size_t)DIN * HD;
    unsigned short* Wtv = Wtk + (size_t)DIN * HD;
    // total ws: 4*33.5MB + 3*2.1MB ~= 140.5 MB

    dim3 wtg(HD / 32, DIN / 32), wtb(32, 8);
    wt_kernel<<<wtg, wtb, 0, stream>>>(Wq, Wtq);
    wt_kernel<<<wtg, wtb, 0, stream>>>(Wk, Wtk);
    wt_kernel<<<wtg, wtb, 0, stream>>>(Wv, Wtv);

    dim3 gg(HD / BN, M / BM);
    gemm_kernel<<<gg, 256, 0, stream>>>(x, Wtq, bq, Qb);
    gemm_kernel<<<gg, 256, 0, stream>>>(y, Wtk, bk, Kb);
    gemm_kernel<<<gg, 256, 0, stream>>>(y, Wtv, bv, Vb);

    vt_kernel<<<dim3(L2D / 64, BATCH * NH), 256, 0, stream>>>(Vb, Vtb);

    attn_kernel<<<dim3(L1D / 64, BATCH * NH), 256, 0, stream>>>(Qb, Kb, Vtb, ym, outp);
}

// Round 2
// 473.726 us; speedup vs baseline: 1.4192x; 1.4192x over previous
//
#include <hip/hip_runtime.h>
#include <hip/hip_bf16.h>

// MultiAttnMatch — cross attention
// B=16, L1=1024, L2=1024, DIN=1024, H=16, DK=DV=64
#define BATCH 16
#define L1D 1024
#define L2D 1024
#define DIN 1024
#define NH 16
#define HD 1024  // NH*DK = NH*DV

typedef __attribute__((ext_vector_type(4))) float floatx4;
typedef __attribute__((ext_vector_type(8))) short shortx8;
typedef __attribute__((ext_vector_type(8))) unsigned short ushortx8;
typedef __attribute__((ext_vector_type(4))) unsigned short ushortx4;

#if __has_builtin(__builtin_amdgcn_exp2f)
#define EXP2(x) __builtin_amdgcn_exp2f(x)
#else
#define EXP2(x) exp2f(x)
#endif

static __device__ __forceinline__ unsigned short f2bf(float f) {  // RNE
    union { float f; unsigned u; } v; v.f = f;
    unsigned r = v.u + 0x7fff + ((v.u >> 16) & 1);
    return (unsigned short)(r >> 16);
}
static __device__ __forceinline__ unsigned short f2bf_fast(float f) {  // round-half-up
    union { float f; unsigned u; } v; v.f = f;
    return (unsigned short)((v.u + 0x8000u) >> 16);
}

#define GLOBAL_AS __attribute__((address_space(1)))
#define LDS_AS __attribute__((address_space(3)))
static __device__ __forceinline__ void gl2lds16(const unsigned short* g, unsigned short* l) {
    __builtin_amdgcn_global_load_lds((const GLOBAL_AS unsigned int*)g,
                                     (LDS_AS unsigned int*)l, 16, 0, 0);
}

// ---------------------------------------------------------------------------
// fp32 -> bf16 convert (8 elem/thread), n divisible by 2048
// ---------------------------------------------------------------------------
__global__ void cvt_kernel(const float* __restrict__ in, unsigned short* __restrict__ out) {
    size_t i = ((size_t)blockIdx.x * 256 + threadIdx.x) * 8;
    float4 a = *(const float4*)(in + i);
    float4 b = *(const float4*)(in + i + 4);
    ushortx8 o;
    o[0] = f2bf(a.x); o[1] = f2bf(a.y); o[2] = f2bf(a.z); o[3] = f2bf(a.w);
    o[4] = f2bf(b.x); o[5] = f2bf(b.y); o[6] = f2bf(b.z); o[7] = f2bf(b.w);
    *(ushortx8*)(out + i) = o;
}

// mask int32 -> float bias (0 / -inf)
__global__ void bias_kernel(const int* __restrict__ ym, float* __restrict__ bias) {
    int i = blockIdx.x * 256 + threadIdx.x;
    bias[i] = ym[i] ? -INFINITY : 0.0f;
}

// ---------------------------------------------------------------------------
// W [DIN][HD] fp32 -> Wt [HD][DIN] bf16 (transpose + convert)
// ---------------------------------------------------------------------------
__global__ void wt_kernel(const float* __restrict__ W, unsigned short* __restrict__ Wt) {
    __shared__ float tile[32][33];
    int bx = blockIdx.x, by = blockIdx.y;
    int tx = threadIdx.x, ty = threadIdx.y;
    for (int i = 0; i < 4; i++)
        tile[ty + i * 8][tx] = W[(size_t)(by * 32 + ty + i * 8) * HD + bx * 32 + tx];
    __syncthreads();
    for (int i = 0; i < 4; i++)
        Wt[(size_t)(bx * 32 + ty + i * 8) * DIN + by * 32 + tx] = f2bf(tile[tx][ty + i * 8]);
}

// ---------------------------------------------------------------------------
// GEMM (all-bf16, m97-style global_load_lds):
//   A [M][1024] bf16 k-contig;  Bt [1024][1024] bf16 n-major k-contig
//   Out[m][n] = bf16( (A@B + bias) * scale )
// Tile 128x128, BK=32, 4 waves (2x2 of 64x64), 16x16x32 bf16 MFMA.
// ---------------------------------------------------------------------------
__global__ __launch_bounds__(256, 2) void gemm_kernel(
    const unsigned short* __restrict__ A, const unsigned short* __restrict__ Bt,
    const float* __restrict__ bias, unsigned short* __restrict__ Out, float scale)
{
    __shared__ unsigned short As[128 * 32];
    __shared__ unsigned short Bs[128 * 32];
    const int m0 = blockIdx.y * 128;
    const int n0 = blockIdx.x * 128;
    const int tid = threadIdx.x;
    const int wid = tid >> 6, lane = tid & 63;
    const int c = lane & 15, qd = lane >> 4;
    const int wm = (wid >> 1) * 64, wn = (wid & 1) * 64;

    floatx4 acc[4][4] = {};

    for (int k0 = 0; k0 < DIN; k0 += 32) {
        for (int i = 0; i < 2; i++) {
            int f16 = i * 256 + tid;          // 16B chunk id; lds dest = base+lane*16
            int row = f16 >> 2;
            int cb  = (f16 & 3) * 8;
            gl2lds16(A  + (size_t)(m0 + row) * DIN + k0 + cb, &As[f16 * 8]);
            gl2lds16(Bt + (size_t)(n0 + row) * DIN + k0 + cb, &Bs[f16 * 8]);
        }
        __syncthreads();

        shortx8 a[4], b[4];
        for (int mt = 0; mt < 4; mt++)
            a[mt] = *(shortx8*)(&As[(wm + mt * 16 + c) * 32 + qd * 8]);
        for (int nt = 0; nt < 4; nt++)
            b[nt] = *(shortx8*)(&Bs[(wn + nt * 16 + c) * 32 + qd * 8]);
        for (int mt = 0; mt < 4; mt++)
            for (int nt = 0; nt < 4; nt++)
                acc[mt][nt] = __builtin_amdgcn_mfma_f32_16x16x32_bf16(
                    a[mt], b[nt], acc[mt][nt], 0, 0, 0);
        __syncthreads();
    }

    for (int nt = 0; nt < 4; nt++) {
        int gn = n0 + wn + nt * 16 + c;
        float bv = bias[gn];
        for (int mt = 0; mt < 4; mt++)
            for (int r = 0; r < 4; r++) {
                int gm = m0 + wm + mt * 16 + qd * 4 + r;
                Out[(size_t)gm * HD + gn] = f2bf((acc[mt][nt][r] + bv) * scale);
            }
    }
}

// ---------------------------------------------------------------------------
// V [b*L2+l2][h*64+dv] bf16 -> Vt [(b*16+h)*64+dv][l2] bf16
// ---------------------------------------------------------------------------
__global__ void vt_kernel(const unsigned short* __restrict__ V,
                          unsigned short* __restrict__ Vt) {
    __shared__ unsigned short t[64][72];
    const int l20 = blockIdx.x * 64;
    const int bh  = blockIdx.y;
    const int b = bh >> 4, h = bh & 15;
    const int tid = threadIdx.x;
    for (int i = 0; i < 2; i++) {
        int idx = i * 256 + tid;
        int row = idx >> 3, col = (idx & 7) * 8;
        *(ushortx8*)(&t[row][col]) =
            *(const ushortx8*)(V + (size_t)(b * L2D + l20 + row) * HD + h * 64 + col);
    }
    __syncthreads();
    for (int i = 0; i < 2; i++) {
        int idx = i * 256 + tid;
        int dv = idx >> 3, col = (idx & 7) * 8;
        ushortx8 v;
        for (int j = 0; j < 8; j++) v[j] = t[col + j][dv];
        *(ushortx8*)(Vt + (size_t)(bh * 64 + dv) * L2D + l20 + col) = v;
    }
}

// ---------------------------------------------------------------------------
// Attention, no-max softmax (exp2 domain; scale baked into Q).
// Q-block 128 (wave: 32 rows), KV tiles of 64.
//   Q,K: [b*len+l][h*64+d] bf16; Vt: [(b*16+h)*64+dv][l2] bf16
//   biasf: [b][l2] float (0 or -inf); out: [b][l1][h*64+dv] fp32
// ---------------------------------------------------------------------------
__global__ __launch_bounds__(256, 4) void attn_kernel(
    const unsigned short* __restrict__ Q, const unsigned short* __restrict__ K,
    const unsigned short* __restrict__ Vt, const float* __restrict__ biasf,
    float* __restrict__ out)
{
    __shared__ unsigned short Ks[64 * 72];
    __shared__ unsigned short Vs[64 * 72];
    __shared__ unsigned short Ps[4][32 * 72];

    const int q0  = blockIdx.x * 128;
    const int bh  = blockIdx.y;
    const int b = bh >> 4, h = bh & 15;
    const int tid = threadIdx.x, wid = tid >> 6, lane = tid & 63;
    const int c = lane & 15, qd = lane >> 4;

    // Q A-fragments: rows q0 + wid*32 + mt2*16 + c  (Q pre-scaled by 0.125*log2e)
    shortx8 qf[2][2];
    for (int mt2 = 0; mt2 < 2; mt2++)
        for (int kt = 0; kt < 2; kt++)
            qf[mt2][kt] = *(const shortx8*)(Q +
                (size_t)(b * L1D + q0 + wid * 32 + mt2 * 16 + c) * HD + h * 64 + kt * 32 + qd * 8);

    floatx4 o[2][4] = {};
    float psum[2][4] = {};

    const unsigned short* Kbase = K + (size_t)b * L2D * HD + h * 64;
    const unsigned short* Vbase = Vt + (size_t)bh * 64 * L2D;
    const float* bb = biasf + b * L2D;

    for (int kv0 = 0; kv0 < L2D; kv0 += 64) {
        for (int i = 0; i < 2; i++) {
            int idx = i * 256 + tid;
            int row = idx >> 3, col = (idx & 7) * 8;
            *(ushortx8*)(&Ks[row * 72 + col]) =
                *(const ushortx8*)(Kbase + (size_t)(kv0 + row) * HD + col);
            *(ushortx8*)(&Vs[row * 72 + col]) =
                *(const ushortx8*)(Vbase + (size_t)row * L2D + kv0 + col);
        }
        __syncthreads();

        float bv[4];
        for (int nt = 0; nt < 4; nt++) bv[nt] = bb[kv0 + nt * 16 + c];

        for (int mt2 = 0; mt2 < 2; mt2++) {
            for (int nt = 0; nt < 4; nt++) {
                floatx4 z = {};
                for (int kt = 0; kt < 2; kt++) {
                    shortx8 kf = *(shortx8*)(&Ks[(nt * 16 + c) * 72 + kt * 32 + qd * 8]);
                    z = __builtin_amdgcn_mfma_f32_16x16x32_bf16(qf[mt2][kt], kf, z, 0, 0, 0);
                }
                // p = exp2(s + bias); bias = -inf => 0
                for (int r = 0; r < 4; r++) {
                    float p = EXP2(z[r] + bv[nt]);
                    psum[mt2][r] += p;
                    Ps[wid][(mt2 * 16 + qd * 4 + r) * 72 + nt * 16 + c] = f2bf_fast(p);
                }
            }
        }
        // O += P @ V (P re-read in A-layout from this wave's private LDS region)
        for (int mt2 = 0; mt2 < 2; mt2++) {
            shortx8 pf[2];
            for (int kt = 0; kt < 2; kt++)
                pf[kt] = *(shortx8*)(&Ps[wid][(mt2 * 16 + c) * 72 + kt * 32 + qd * 8]);
            for (int nt = 0; nt < 4; nt++)
                for (int kt = 0; kt < 2; kt++) {
                    shortx8 vf = *(shortx8*)(&Vs[(nt * 16 + c) * 72 + kt * 32 + qd * 8]);
                    o[mt2][nt] = __builtin_amdgcn_mfma_f32_16x16x32_bf16(pf[kt], vf, o[mt2][nt], 0, 0, 0);
                }
        }
        __syncthreads();
    }

    // l reduction deferred to here: sum over 16 lanes of each quad-row group
    for (int mt2 = 0; mt2 < 2; mt2++)
        for (int r = 0; r < 4; r++) {
            float l = psum[mt2][r];
            for (int off = 1; off < 16; off <<= 1)
                l += __shfl_xor(l, off, 64);
            float inv = 1.0f / l;
            size_t rowbase = ((size_t)b * L1D + q0 + wid * 32 + mt2 * 16 + qd * 4 + r) * HD + h * 64;
            for (int nt = 0; nt < 4; nt++)
                out[rowbase + nt * 16 + c] = o[mt2][nt][r] * inv;
        }
}

// ---------------------------------------------------------------------------
extern "C" void kernel_launch(void* const* d_in, const int* in_sizes, int n_in,
                              void* d_out, int out_size, void* d_ws, size_t ws_size,
                              hipStream_t stream) {
    const float* x  = (const float*)d_in[0];
    const float* y  = (const float*)d_in[1];
    const int*  ym  = (const int*)d_in[2];
    const float* Wq = (const float*)d_in[3];
    const float* bq = (const float*)d_in[4];
    const float* Wk = (const float*)d_in[5];
    const float* bk = (const float*)d_in[6];
    const float* Wv = (const float*)d_in[7];
    const float* bv = (const float*)d_in[8];
    float* outp = (float*)d_out;

    const size_t M = (size_t)BATCH * L1D;      // 16384
    const size_t T = M * HD;                   // 16.7M elems
    unsigned short* Qb  = (unsigned short*)d_ws;
    unsigned short* Kb  = Qb + T;
    unsigned short* Vb  = Kb + T;
    unsigned short* S1  = Vb + T;              // xb, then Vt (xb dead after Q GEMM)
    unsigned short* S2  = S1 + T;              // yb
    unsigned short* Wt  = S2 + T;              // shared by the 3 weight transposes
    float* biasf        = (float*)(Wt + (size_t)DIN * HD);
    // total ~162 MB

    const float QSCALE = 0.125f * 1.44269504088896340736f;  // 1/sqrt(64) * log2(e)

    cvt_kernel<<<T / 2048, 256, 0, stream>>>(x, S1);
    cvt_kernel<<<T / 2048, 256, 0, stream>>>(y, S2);
    bias_kernel<<<(BATCH * L2D) / 256, 256, 0, stream>>>(ym, biasf);

    dim3 wtg(HD / 32, DIN / 32), wtb(32, 8);
    dim3 gg(HD / 128, M / 128);
    wt_kernel<<<wtg, wtb, 0, stream>>>(Wq, Wt);
    gemm_kernel<<<gg, 256, 0, stream>>>(S1, Wt, bq, Qb, QSCALE);
    wt_kernel<<<wtg, wtb, 0, stream>>>(Wk, Wt);
    gemm_kernel<<<gg, 256, 0, stream>>>(S2, Wt, bk, Kb, 1.0f);
    wt_kernel<<<wtg, wtb, 0, stream>>>(Wv, Wt);
    gemm_kernel<<<gg, 256, 0, stream>>>(S2, Wt, bv, Vb, 1.0f);

    vt_kernel<<<dim3(L2D / 64, BATCH * NH), 256, 0, stream>>>(Vb, S1);

    attn_kernel<<<dim3(L1D / 128, BATCH * NH), 256, 0, stream>>>(Qb, Kb, S1, biasf, outp);
}

// Round 3
// 419.608 us; speedup vs baseline: 1.6022x; 1.1290x over previous
//
#include <hip/hip_runtime.h>
#include <hip/hip_bf16.h>

// MultiAttnMatch — cross attention
// B=16, L1=1024, L2=1024, DIN=1024, H=16, DK=DV=64
#define BATCH 16
#define L1D 1024
#define L2D 1024
#define DIN 1024
#define NH 16
#define HD 1024   // NH*DK = NH*DV (output row stride)
#define OHD 3072  // fused QKV row stride

typedef __attribute__((ext_vector_type(4))) float floatx4;
typedef __attribute__((ext_vector_type(8))) short shortx8;
typedef __attribute__((ext_vector_type(8))) unsigned short ushortx8;

#if __has_builtin(__builtin_amdgcn_exp2f)
#define EXP2(x) __builtin_amdgcn_exp2f(x)
#else
#define EXP2(x) exp2f(x)
#endif

static __device__ __forceinline__ unsigned short f2bf(float f) {  // RNE
    union { float f; unsigned u; } v; v.f = f;
    unsigned r = v.u + 0x7fff + ((v.u >> 16) & 1);
    return (unsigned short)(r >> 16);
}
static __device__ __forceinline__ unsigned short f2bf_fast(float f) {  // round-half-up
    union { float f; unsigned u; } v; v.f = f;
    return (unsigned short)((v.u + 0x8000u) >> 16);
}

#define GLOBAL_AS __attribute__((address_space(1)))
#define LDS_AS __attribute__((address_space(3)))
static __device__ __forceinline__ void gl2lds16(const unsigned short* g, unsigned short* l) {
    __builtin_amdgcn_global_load_lds((const GLOBAL_AS unsigned int*)g,
                                     (LDS_AS unsigned int*)l, 16, 0, 0);
}

// ---------------------------------------------------------------------------
// prep: cvt x -> xb, cvt y -> yb (fp32->bf16, 8/thread), mask -> float bias
// ---------------------------------------------------------------------------
#define NCVT 8192  // T/2048 blocks per tensor
__global__ void prep_kernel(const float* __restrict__ x, const float* __restrict__ y,
                            unsigned short* __restrict__ xb, unsigned short* __restrict__ yb,
                            const int* __restrict__ ym, float* __restrict__ biasf) {
    int bid = blockIdx.x;
    if (bid < 2 * NCVT) {
        const float* in = bid < NCVT ? x : y;
        unsigned short* o = bid < NCVT ? xb : yb;
        int bb = bid < NCVT ? bid : bid - NCVT;
        size_t i = ((size_t)bb * 256 + threadIdx.x) * 8;
        float4 a = *(const float4*)(in + i);
        float4 b = *(const float4*)(in + i + 4);
        ushortx8 v;
        v[0] = f2bf(a.x); v[1] = f2bf(a.y); v[2] = f2bf(a.z); v[3] = f2bf(a.w);
        v[4] = f2bf(b.x); v[5] = f2bf(b.y); v[6] = f2bf(b.z); v[7] = f2bf(b.w);
        *(ushortx8*)(o + i) = v;
    } else {
        int i = (bid - 2 * NCVT) * 256 + threadIdx.x;
        biasf[i] = ym[i] ? -INFINITY : 0.0f;
    }
}

// ---------------------------------------------------------------------------
// W [DIN][HD] fp32 -> Wt [3*HD][DIN] bf16 (transpose + convert), z = section
// ---------------------------------------------------------------------------
__global__ void wt_kernel(const float* __restrict__ Wq, const float* __restrict__ Wk,
                          const float* __restrict__ Wv, unsigned short* __restrict__ Wt) {
    __shared__ float tile[32][33];
    const float* W = blockIdx.z == 0 ? Wq : (blockIdx.z == 1 ? Wk : Wv);
    unsigned short* dst = Wt + (size_t)blockIdx.z * HD * DIN;
    int bx = blockIdx.x, by = blockIdx.y;
    int tx = threadIdx.x, ty = threadIdx.y;
    for (int i = 0; i < 4; i++)
        tile[ty + i * 8][tx] = W[(size_t)(by * 32 + ty + i * 8) * HD + bx * 32 + tx];
    __syncthreads();
    for (int i = 0; i < 4; i++)
        dst[(size_t)(bx * 32 + ty + i * 8) * DIN + by * 32 + tx] = f2bf(tile[tx][ty + i * 8]);
}

// ---------------------------------------------------------------------------
// Fused QKV GEMM: Out[m][3072] = bf16((A_sec @ W_sec + bias_sec) * scale_sec)
//   A: xb (sec 0) / yb (sec 1,2), [16384][1024] bf16 k-contig
//   Wt: [3072][1024] bf16 n-major k-contig
// Tile 128x128, BK=32, global_load_lds + XOR chunk swizzle (2-way banks).
// ---------------------------------------------------------------------------
__global__ __launch_bounds__(256, 2) void gemm_kernel(
    const unsigned short* __restrict__ xb, const unsigned short* __restrict__ yb,
    const unsigned short* __restrict__ Wt,
    const float* __restrict__ bq, const float* __restrict__ bk, const float* __restrict__ bvp,
    unsigned short* __restrict__ Out, float qscale)
{
    __shared__ unsigned short As[128 * 32];
    __shared__ unsigned short Bs[128 * 32];
    const int n0 = blockIdx.x * 128;       // 0..3071
    const int m0 = blockIdx.y * 128;
    const int sec = n0 >> 10;
    const unsigned short* A = (sec == 0) ? xb : yb;
    const float* bias = (sec == 0) ? bq : (sec == 1 ? bk : bvp);
    const float scale = (sec == 0) ? qscale : 1.0f;

    const int tid = threadIdx.x;
    const int wid = tid >> 6, lane = tid & 63;
    const int c = lane & 15, qd = lane >> 4;
    const int wm = (wid >> 1) * 64, wn = (wid & 1) * 64;

    // staging indices (loop-invariant): 16B chunk f16 -> row, swizzled col
    int f16a = tid, f16b = 256 + tid;
    int rowA = f16a >> 2, scA = ((f16a & 3) ^ ((rowA >> 1) & 3)) * 8;
    int rowB = f16b >> 2, scB = ((f16b & 3) ^ ((rowB >> 1) & 3)) * 8;
    // fragment read swizzle (chunk = qd, xor (row>>1)&3 = (c>>1)&3)
    const int swz = (qd ^ ((c >> 1) & 3)) * 8;

    floatx4 acc[4][4] = {};

    for (int k0 = 0; k0 < DIN; k0 += 32) {
        gl2lds16(A  + (size_t)(m0 + rowA) * DIN + k0 + scA, &As[f16a * 8]);
        gl2lds16(Wt + (size_t)(n0 + rowA) * DIN + k0 + scA, &Bs[f16a * 8]);
        gl2lds16(A  + (size_t)(m0 + rowB) * DIN + k0 + scB, &As[f16b * 8]);
        gl2lds16(Wt + (size_t)(n0 + rowB) * DIN + k0 + scB, &Bs[f16b * 8]);
        __syncthreads();

        shortx8 a[4], b[4];
        for (int mt = 0; mt < 4; mt++)
            a[mt] = *(shortx8*)(&As[(wm + mt * 16 + c) * 32 + swz]);
        for (int nt = 0; nt < 4; nt++)
            b[nt] = *(shortx8*)(&Bs[(wn + nt * 16 + c) * 32 + swz]);
        for (int mt = 0; mt < 4; mt++)
            for (int nt = 0; nt < 4; nt++)
                acc[mt][nt] = __builtin_amdgcn_mfma_f32_16x16x32_bf16(
                    a[mt], b[nt], acc[mt][nt], 0, 0, 0);
        __syncthreads();
    }

    for (int nt = 0; nt < 4; nt++) {
        int gn = n0 + wn + nt * 16 + c;
        float bv = bias[gn & 1023];
        for (int mt = 0; mt < 4; mt++)
            for (int r = 0; r < 4; r++) {
                int gm = m0 + wm + mt * 16 + qd * 4 + r;
                Out[(size_t)gm * OHD + gn] = f2bf((acc[mt][nt][r] + bv) * scale);
            }
    }
}

// ---------------------------------------------------------------------------
// V (Obuf cols 2048..3071, stride 3072) -> Vt [(b*16+h)*64+dv][l2] bf16
// ---------------------------------------------------------------------------
__global__ void vt_kernel(const unsigned short* __restrict__ V,
                          unsigned short* __restrict__ Vt) {
    __shared__ unsigned short t[64][72];
    const int l20 = blockIdx.x * 64;
    const int bh  = blockIdx.y;
    const int b = bh >> 4, h = bh & 15;
    const int tid = threadIdx.x;
    for (int i = 0; i < 2; i++) {
        int idx = i * 256 + tid;
        int row = idx >> 3, col = (idx & 7) * 8;
        *(ushortx8*)(&t[row][col]) =
            *(const ushortx8*)(V + (size_t)(b * L2D + l20 + row) * OHD + h * 64 + col);
    }
    __syncthreads();
    for (int i = 0; i < 2; i++) {
        int idx = i * 256 + tid;
        int dv = idx >> 3, col = (idx & 7) * 8;
        ushortx8 v;
        for (int j = 0; j < 8; j++) v[j] = t[col + j][dv];
        *(ushortx8*)(Vt + (size_t)(bh * 64 + dv) * L2D + l20 + col) = v;
    }
}

// ---------------------------------------------------------------------------
// Attention: no-max exp2 softmax, Q-block 128, KV tiles 64.
// K/V staged via global_load_lds with XOR chunk swizzle (2-way banks).
// XCD-aware block remap so the 8 q-blocks of one (b,h) share one L2.
// ---------------------------------------------------------------------------
__global__ __launch_bounds__(256, 4) void attn_kernel(
    const unsigned short* __restrict__ QK,   // Obuf: Q = col 0, K = col 1024
    const unsigned short* __restrict__ Vt, const float* __restrict__ biasf,
    float* __restrict__ out)
{
    __shared__ unsigned short Ks[64 * 64];
    __shared__ unsigned short Vs[64 * 64];
    __shared__ unsigned short Ps[4][32 * 72];

    // remap: same-XCD blocks (flat%8) share bh
    int f = blockIdx.y * gridDim.x + blockIdx.x;   // 0..2047
    int bh = (f & 7) * 32 + (f >> 6);
    int q0 = ((f >> 3) & 7) * 128;
    const int b = bh >> 4, h = bh & 15;
    const int tid = threadIdx.x, wid = tid >> 6, lane = tid & 63;
    const int c = lane & 15, qd = lane >> 4;

    // Q A-fragments (Q pre-scaled by 0.125*log2e in GEMM epilogue)
    shortx8 qf[2][2];
    for (int mt2 = 0; mt2 < 2; mt2++)
        for (int kt = 0; kt < 2; kt++)
            qf[mt2][kt] = *(const shortx8*)(QK +
                (size_t)(b * L1D + q0 + wid * 32 + mt2 * 16 + c) * OHD + h * 64 + kt * 32 + qd * 8);

    floatx4 o[2][4] = {};
    float psum[2][4] = {};

    const unsigned short* Kbase = QK + HD + (size_t)b * L2D * OHD + h * 64;
    const unsigned short* Vbase = Vt + (size_t)bh * 64 * L2D;
    const float* bb = biasf + b * L2D;

    // staging indices (loop-invariant)
    int idxa = tid, idxb = 256 + tid;
    int rowa = idxa >> 3, sca = ((idxa & 7) ^ (rowa & 7)) * 8;
    int rowb = idxb >> 3, scb = ((idxb & 7) ^ (rowb & 7)) * 8;
    const int swz8 = c & 7;  // frag-read xor

    for (int kv0 = 0; kv0 < L2D; kv0 += 64) {
        gl2lds16(Kbase + (size_t)(kv0 + rowa) * OHD + sca, &Ks[idxa * 8]);
        gl2lds16(Vbase + (size_t)rowa * L2D + kv0 + sca, &Vs[idxa * 8]);
        gl2lds16(Kbase + (size_t)(kv0 + rowb) * OHD + scb, &Ks[idxb * 8]);
        gl2lds16(Vbase + (size_t)rowb * L2D + kv0 + scb, &Vs[idxb * 8]);
        __syncthreads();

        float bv[4];
        for (int nt = 0; nt < 4; nt++) bv[nt] = bb[kv0 + nt * 16 + c];

        for (int mt2 = 0; mt2 < 2; mt2++) {
            for (int nt = 0; nt < 4; nt++) {
                floatx4 z = {};
                for (int kt = 0; kt < 2; kt++) {
                    shortx8 kf = *(shortx8*)(&Ks[(nt * 16 + c) * 64 + ((kt * 4 + qd) ^ swz8) * 8]);
                    z = __builtin_amdgcn_mfma_f32_16x16x32_bf16(qf[mt2][kt], kf, z, 0, 0, 0);
                }
                for (int r = 0; r < 4; r++) {
                    float p = EXP2(z[r] + bv[nt]);
                    psum[mt2][r] += p;
                    Ps[wid][(mt2 * 16 + qd * 4 + r) * 72 + nt * 16 + c] = f2bf_fast(p);
                }
            }
        }
        for (int mt2 = 0; mt2 < 2; mt2++) {
            shortx8 pf[2];
            for (int kt = 0; kt < 2; kt++)
                pf[kt] = *(shortx8*)(&Ps[wid][(mt2 * 16 + c) * 72 + kt * 32 + qd * 8]);
            for (int nt = 0; nt < 4; nt++)
                for (int kt = 0; kt < 2; kt++) {
                    shortx8 vf = *(shortx8*)(&Vs[(nt * 16 + c) * 64 + ((kt * 4 + qd) ^ swz8) * 8]);
                    o[mt2][nt] = __builtin_amdgcn_mfma_f32_16x16x32_bf16(pf[kt], vf, o[mt2][nt], 0, 0, 0);
                }
        }
        __syncthreads();
    }

    for (int mt2 = 0; mt2 < 2; mt2++)
        for (int r = 0; r < 4; r++) {
            float l = psum[mt2][r];
            for (int off = 1; off < 16; off <<= 1)
                l += __shfl_xor(l, off, 64);
            float inv = 1.0f / l;
            size_t rowbase = ((size_t)b * L1D + q0 + wid * 32 + mt2 * 16 + qd * 4 + r) * HD + h * 64;
            for (int nt = 0; nt < 4; nt++)
                out[rowbase + nt * 16 + c] = o[mt2][nt][r] * inv;
        }
}

// ---------------------------------------------------------------------------
extern "C" void kernel_launch(void* const* d_in, const int* in_sizes, int n_in,
                              void* d_out, int out_size, void* d_ws, size_t ws_size,
                              hipStream_t stream) {
    const float* x  = (const float*)d_in[0];
    const float* y  = (const float*)d_in[1];
    const int*  ym  = (const int*)d_in[2];
    const float* Wq = (const float*)d_in[3];
    const float* bq = (const float*)d_in[4];
    const float* Wk = (const float*)d_in[5];
    const float* bk = (const float*)d_in[6];
    const float* Wv = (const float*)d_in[7];
    const float* bv = (const float*)d_in[8];
    float* outp = (float*)d_out;

    const size_t M = (size_t)BATCH * L1D;      // 16384
    const size_t T = M * HD;                   // 16.78M
    unsigned short* Obuf = (unsigned short*)d_ws;     // M*3072 (QKV fused)
    unsigned short* xb   = Obuf + M * OHD;            // T ; reused as Vt after gemm
    unsigned short* yb   = xb + T;                    // T
    unsigned short* Wt   = yb + T;                    // 3072*1024
    float* biasf         = (float*)(Wt + (size_t)OHD * DIN);
    // total ~174 MB

    const float QSCALE = 0.125f * 1.44269504088896340736f;  // 1/sqrt(64)*log2(e)

    prep_kernel<<<2 * NCVT + (BATCH * L2D) / 256, 256, 0, stream>>>(x, y, xb, yb, ym, biasf);
    wt_kernel<<<dim3(HD / 32, DIN / 32, 3), dim3(32, 8), 0, stream>>>(Wq, Wk, Wv, Wt);
    gemm_kernel<<<dim3(OHD / 128, M / 128), 256, 0, stream>>>(xb, yb, Wt, bq, bk, bv, Obuf, QSCALE);
    vt_kernel<<<dim3(L2D / 64, BATCH * NH), 256, 0, stream>>>(Obuf + 2 * HD, xb);
    attn_kernel<<<dim3(L1D / 128, BATCH * NH), 256, 0, stream>>>(Obuf, xb, biasf, outp);
}